// Round 1
// baseline (197.333 us; speedup 1.0000x reference)
//
#include <hip/hip_runtime.h>
#include <hip/hip_bf16.h>

#define NH   8
#define HID  256
#define VD   32
#define NQ   2048
#define NKK  2048
#define NB   16
#define NN   512   // NB*VD

typedef short bf16x8 __attribute__((ext_vector_type(8)));
typedef float f32x4 __attribute__((ext_vector_type(4)));

__device__ inline unsigned short f2bf(float f) {
  unsigned int u = __float_as_uint(f);
  u += 0x7FFFu + ((u >> 16) & 1u);   // RNE
  return (unsigned short)(u >> 16);
}

__device__ inline void gload_lds16(const void* g, void* l) {
  __builtin_amdgcn_global_load_lds(
      (const __attribute__((address_space(1))) void*)g,
      (__attribute__((address_space(3))) void*)l, 16, 0, 0);
}

__device__ inline float gelu_f(float x) {
  // jax.nn.gelu default: approximate (tanh)
  float x3 = x * x * x;
  float u = 0.7978845608028654f * (x + 0.044715f * x3);
  float th = tanhf(u);
  return 0.5f * x * (1.0f + th);
}

// ---------------- kernel 1: value^T[h][b*32+v][k] = sum_j x[b,k,j] * w[h,j,v] (bf16 out)
__global__ __launch_bounds__(256) void value_kernel(
    const float* __restrict__ x, const float* __restrict__ w,
    unsigned short* __restrict__ vT) {
  const int kt = blockIdx.x;   // 0..63 (32 k-rows each)
  const int b  = blockIdx.y;   // 0..15
  const int k0 = kt * 32;
  const int t  = threadIdx.x;

  __shared__ float xs[256][36];   // [j][r], pad 36 (16B-aligned rows, 8-way store conflict only)
  const float* xp = x + ((size_t)b * NKK + k0) * HID;
  for (int i = t; i < 32 * 256; i += 256) {
    int r = i >> 8, j = i & 255;
    xs[j][r] = xp[i];
  }
  __syncthreads();

  const int h = t >> 5, v = t & 31;
  const float* wp = w + (size_t)h * HID * VD + v;
  float acc[32];
#pragma unroll
  for (int i = 0; i < 32; ++i) acc[i] = 0.f;

  for (int j = 0; j < 256; ++j) {
    float wj = wp[(size_t)j * VD];
    const f32x4* row = (const f32x4*)&xs[j][0];
#pragma unroll
    for (int q4 = 0; q4 < 8; ++q4) {
      f32x4 xv = row[q4];             // broadcast ds_read_b128
#pragma unroll
      for (int e = 0; e < 4; ++e) acc[q4 * 4 + e] += xv[e] * wj;
    }
  }

  unsigned short* vp = vT + ((size_t)h * NN + b * VD + v) * NKK + k0;
#pragma unroll
  for (int i = 0; i < 4; ++i) {       // 4 x 16B stores
    uint4 pk;
    pk.x = (unsigned)f2bf(acc[i * 8 + 0]) | ((unsigned)f2bf(acc[i * 8 + 1]) << 16);
    pk.y = (unsigned)f2bf(acc[i * 8 + 2]) | ((unsigned)f2bf(acc[i * 8 + 3]) << 16);
    pk.z = (unsigned)f2bf(acc[i * 8 + 4]) | ((unsigned)f2bf(acc[i * 8 + 5]) << 16);
    pk.w = (unsigned)f2bf(acc[i * 8 + 6]) | ((unsigned)f2bf(acc[i * 8 + 7]) << 16);
    *(uint4*)(vp + i * 8) = pk;
  }
}

// ---------------- kernel 2: per (h,q) row: median threshold + masked softmax -> att bf16
__global__ __launch_bounds__(256) void att_kernel(
    const float* __restrict__ m_dist, const float* __restrict__ r,
    unsigned short* __restrict__ att) {
  const int row = blockIdx.x;          // h*NQ + q
  const int h = row >> 11;
  const int t = threadIdx.x;
  const int wid = t >> 6;
  const float* md = m_dist + (size_t)row * NKK;

  __shared__ unsigned int hist[256];
  __shared__ float coll[160];
  __shared__ unsigned int collCnt;
  __shared__ int sBA, sBB;
  __shared__ unsigned int sBelow;
  __shared__ unsigned int wtot[4];
  __shared__ float wmin[4], wsumsh[4];
  __shared__ float sVa, sVb;

  float rr = r[h];
  const float C = (float)(0.25 * 3.141592653589793 * (1.0 - 1e-7));
  float sc = tanf(C * (1.0f + sinf(rr)));

  hist[t] = 0u;
  if (t == 0) collCnt = 0u;
  __syncthreads();

  float m[8];
#pragma unroll
  for (int j = 0; j < 8; ++j) m[j] = md[t + 256 * j];

  float mn = m[0];
#pragma unroll
  for (int j = 1; j < 8; ++j) mn = fminf(mn, m[j]);
#pragma unroll
  for (int j = 0; j < 8; ++j) {
    int bin = (int)(m[j] * 256.0f);
    bin = min(max(bin, 0), 255);
    atomicAdd(&hist[bin], 1u);
  }
#pragma unroll
  for (int off = 32; off > 0; off >>= 1) mn = fminf(mn, __shfl_down(mn, off));
  if ((t & 63) == 0) wmin[wid] = mn;
  __syncthreads();

  // inclusive prefix over 256 bins (bin t owned by thread t)
  unsigned int c = hist[t];
  unsigned int xs2 = c;
  for (int off = 1; off < 64; off <<= 1) {
    unsigned int y = __shfl_up(xs2, off);
    if ((t & 63) >= off) xs2 += y;
  }
  if ((t & 63) == 63) wtot[wid] = xs2;
  __syncthreads();
  unsigned int base = 0;
  for (int wq = 0; wq < 4; ++wq)
    if (wq < wid) base += wtot[wq];
  unsigned int cum = xs2 + base;
  if (cum >= 1024u && cum - c < 1024u) { sBA = t; sBelow = cum - c; }
  if (cum >= 1025u && cum - c < 1025u) { sBB = t; }
  __syncthreads();

  const int bA = sBA, bB = sBB;
  const unsigned int below = sBelow;
#pragma unroll
  for (int j = 0; j < 8; ++j) {
    int bin = (int)(m[j] * 256.0f);
    bin = min(max(bin, 0), 255);
    if (bin >= bA && bin <= bB) {
      unsigned int idx = atomicAdd(&collCnt, 1u);
      if (idx < 160u) coll[idx] = m[j];
    }
  }
  __syncthreads();
  const int n = (int)min(collCnt, 160u);
  const int ra = 1023 - (int)below, rb = 1024 - (int)below;
  if (t < n) {
    float v = coll[t];
    int rank = 0;
    for (int j2 = 0; j2 < n; ++j2) {
      float u = coll[j2];
      rank += (u < v || (u == v && j2 < t)) ? 1 : 0;  // stable rank
    }
    if (rank == ra) sVa = v;
    if (rank == rb) sVb = v;
  }
  __syncthreads();

  float mtot = fminf(fminf(wmin[0], wmin[1]), fminf(wmin[2], wmin[3]));
  float minscaled = mtot * sc;
  float ap = sVa * sc, bp = sVb * sc;
  float thr = 0.5f * ap + 0.5f * bp;   // replicate linear interpolation

  float wv[8];
  float wsum = 0.f;
#pragma unroll
  for (int j = 0; j < 8; ++j) {
    float s = m[j] * sc;
    float e = (s <= thr) ? __expf(minscaled - s) : 0.f;
    wv[j] = e;
    wsum += e;
  }
#pragma unroll
  for (int off = 32; off > 0; off >>= 1) wsum += __shfl_down(wsum, off);
  if ((t & 63) == 0) wsumsh[wid] = wsum;
  __syncthreads();
  float denom = wsumsh[0] + wsumsh[1] + wsumsh[2] + wsumsh[3];
  float inv = 1.0f / denom;

  unsigned short* ao = att + (size_t)row * NKK;
#pragma unroll
  for (int j = 0; j < 8; ++j) ao[t + 256 * j] = f2bf(wv[j] * inv);
}

// ---------------- kernel 3: per head GEMM: C[q, n] = att[h] @ vT[h]^T, + gelu, scattered to out
__global__ __launch_bounds__(256) void gemm_kernel(
    const unsigned short* __restrict__ att, const unsigned short* __restrict__ vT,
    float* __restrict__ out) {
  const int bid = blockIdx.x;
  const int h = bid & 7;           // XCD = bid%8 -> one head per XCD (B panel L2-resident)
  const int tile = bid >> 3;       // 0..63
  const int qt = tile >> 2, nt = tile & 3;
  const int q0 = qt * 128, n0 = nt * 128;
  const int t = threadIdx.x;
  const int lane = t & 63, wid = t >> 6;
  const int wr = wid >> 1, wc = wid & 1;

  __shared__ __align__(16) unsigned short As[128 * 32];
  __shared__ __align__(16) unsigned short Bs[128 * 32];

  const int rowL = t >> 2;          // 0..63
  const int cb = (t & 3) * 8;       // k element offset (16B)

  const unsigned short* gA0 = att + ((size_t)h * NQ + q0 + rowL) * NKK + cb;
  const unsigned short* gA1 = gA0 + (size_t)64 * NKK;
  const unsigned short* gB0 = vT + ((size_t)h * NN + n0 + rowL) * NKK + cb;
  const unsigned short* gB1 = gB0 + (size_t)64 * NKK;

  char* lA0 = (char*)As + t * 16;
  char* lA1 = (char*)As + 4096 + t * 16;
  char* lB0 = (char*)Bs + t * 16;
  char* lB1 = (char*)Bs + 4096 + t * 16;

  f32x4 acc[4][4];
#pragma unroll
  for (int i = 0; i < 4; ++i)
#pragma unroll
    for (int j = 0; j < 4; ++j) acc[i][j] = (f32x4){0.f, 0.f, 0.f, 0.f};

  const int fr = lane & 15;
  const int kb = (lane >> 4) * 16;  // byte offset of 8-elem k group
  const char* baseA = (const char*)As + (wr * 64 + fr) * 64 + kb;
  const char* baseB = (const char*)Bs + (wc * 64 + fr) * 64 + kb;

  for (int kt = 0; kt < NKK / 32; ++kt) {
    gload_lds16(gA0, lA0);
    gload_lds16(gA1, lA1);
    gload_lds16(gB0, lB0);
    gload_lds16(gB1, lB1);
    gA0 += 32; gA1 += 32; gB0 += 32; gB1 += 32;
    __syncthreads();   // drains vmcnt before barrier

    bf16x8 a[4], b[4];
#pragma unroll
    for (int i = 0; i < 4; ++i) a[i] = *(const bf16x8*)(baseA + i * 16 * 64);
#pragma unroll
    for (int j = 0; j < 4; ++j) b[j] = *(const bf16x8*)(baseB + j * 16 * 64);
#pragma unroll
    for (int i = 0; i < 4; ++i)
#pragma unroll
      for (int j = 0; j < 4; ++j)
        acc[i][j] = __builtin_amdgcn_mfma_f32_16x16x32_bf16(a[i], b[j], acc[i][j], 0, 0, 0);
    __syncthreads();
  }

  // epilogue: D row=(lane>>4)*4+reg, col=lane&15 ; n -> (b, v) ; out[b, q, h*32+v]
  const int orow = q0 + wr * 64 + (lane >> 4) * 4;
  const int ocol0 = n0 + wc * 64 + (lane & 15);
#pragma unroll
  for (int i = 0; i < 4; ++i) {
#pragma unroll
    for (int j = 0; j < 4; ++j) {
      int ncol = ocol0 + j * 16;
      int bb = ncol >> 5, vv = ncol & 31;
      float* op = out + ((size_t)bb * NQ + orow + i * 16) * HID + h * VD + vv;
#pragma unroll
      for (int e = 0; e < 4; ++e) op[(size_t)e * HID] = gelu_f(acc[i][j][e]);
    }
  }
}

extern "C" void kernel_launch(void* const* d_in, const int* in_sizes, int n_in,
                              void* d_out, int out_size, void* d_ws, size_t ws_size,
                              hipStream_t stream) {
  const float* m_dist = (const float*)d_in[0];  // [8,2048,2048]
  const float* x      = (const float*)d_in[1];  // [16,2048,256]
  const float* r      = (const float*)d_in[2];  // [8]
  const float* weight = (const float*)d_in[3];  // [8,256,32]
  float* out = (float*)d_out;                   // [16,2048,256]

  // workspace: att bf16 (67.1 MB) + vT bf16 (16.8 MB)
  unsigned short* att = (unsigned short*)d_ws;
  unsigned short* vT  = (unsigned short*)((char*)d_ws + (size_t)NH * NQ * NKK * 2);

  value_kernel<<<dim3(NKK / 32, NB), dim3(256), 0, stream>>>(x, weight, vT);
  att_kernel<<<dim3(NH * NQ), dim3(256), 0, stream>>>(m_dist, r, att);
  gemm_kernel<<<dim3(NH * 64), dim3(256), 0, stream>>>(att, vT, out);
}

// Round 2
// 114.856 us; speedup vs baseline: 1.7181x; 1.7181x over previous
//
#include <hip/hip_runtime.h>
#include <hip/hip_bf16.h>

#define NH   8
#define HID  256
#define VD   32
#define NQ   2048
#define NKK  2048
#define NB   16
#define NN   512   // NB*VD

typedef short bf16x8 __attribute__((ext_vector_type(8)));
typedef float f32x4 __attribute__((ext_vector_type(4)));

__device__ inline unsigned short f2bf(float f) {
  unsigned int u = __float_as_uint(f);
  u += 0x7FFFu + ((u >> 16) & 1u);   // RNE
  return (unsigned short)(u >> 16);
}

__device__ inline void gload_lds16(const void* g, void* l) {
  __builtin_amdgcn_global_load_lds(
      (const __attribute__((address_space(1))) void*)g,
      (__attribute__((address_space(3))) void*)l, 16, 0, 0);
}

__device__ inline float gelu_f(float x) {
  // jax.nn.gelu default: approximate (tanh)
  float x3 = x * x * x;
  float u = 0.7978845608028654f * (x + 0.044715f * x3);
  float th = tanhf(u);
  return 0.5f * x * (1.0f + th);
}

// ---------------- kernel 0: wT[h*32+v][j] = bf16(w[h][j][v])
__global__ __launch_bounds__(256) void wt_kernel(
    const float* __restrict__ w, unsigned short* __restrict__ wT) {
  const int n = blockIdx.x;        // 0..255 (h*32+v)
  const int j = threadIdx.x;       // 0..255
  wT[(size_t)n * HID + j] = f2bf(w[(size_t)(n >> 5) * HID * VD + (size_t)j * VD + (n & 31)]);
}

// ---------------- kernel 1: per-b MFMA GEMM: vT[(h,v)][k] = sum_j wT[(h,v)][j] * x[b][k][j]
__global__ __launch_bounds__(256) void value_kernel(
    const unsigned short* __restrict__ wT, const float* __restrict__ x,
    unsigned short* __restrict__ vT) {
  const int hvt = blockIdx.x & 1;      // 0..1  (hv tile)
  const int kt  = blockIdx.x >> 1;     // 0..15 (k tile)
  const int b   = blockIdx.y;          // 0..15
  const int m0 = hvt * 128;            // hv base
  const int n0 = kt * 128;             // k base
  const int t = threadIdx.x;
  const int lane = t & 63, wid = t >> 6;
  const int wr = wid >> 1, wc = wid & 1;

  __shared__ __align__(16) unsigned short As[128 * 32];
  __shared__ __align__(16) unsigned short Bs[128 * 32];

  // A staging via global_load_lds (wT is bf16, K-contig)
  const int rowL = t >> 2, cb = (t & 3) * 8;
  const unsigned short* gA0 = wT + (size_t)(m0 + rowL) * HID + cb;
  const unsigned short* gA1 = gA0 + (size_t)64 * HID;
  char* lA0 = (char*)As + t * 16;
  char* lA1 = (char*)As + 4096 + t * 16;

  // B staging via registers with f32->bf16 (x rows are k-cols of output)
  const int brow = t >> 1, bj = (t & 1) * 16;
  const float* gB = x + ((size_t)b * NKK + n0 + brow) * HID + bj;
  unsigned short* lB = Bs + brow * 32 + bj;

  f32x4 acc[4][4];
#pragma unroll
  for (int i = 0; i < 4; ++i)
#pragma unroll
    for (int j = 0; j < 4; ++j) acc[i][j] = (f32x4){0.f, 0.f, 0.f, 0.f};

  const int fr = lane & 15;
  const int kb = (lane >> 4) * 16;
  const char* baseA = (const char*)As + (wr * 64 + fr) * 64 + kb;
  const char* baseB = (const char*)Bs + (wc * 64 + fr) * 64 + kb;

  // prefetch B step 0
  f32x4 p0 = *(const f32x4*)(gB + 0);
  f32x4 p1 = *(const f32x4*)(gB + 4);
  f32x4 p2 = *(const f32x4*)(gB + 8);
  f32x4 p3 = *(const f32x4*)(gB + 12);

  for (int kk = 0; kk < HID / 32; ++kk) {
    gload_lds16(gA0, lA0);
    gload_lds16(gA1, lA1);
    gA0 += 32; gA1 += 32;

    f32x4 c0 = p0, c1 = p1, c2 = p2, c3 = p3;
    if (kk < HID / 32 - 1) {
      const float* nb = gB + (kk + 1) * 32;
      p0 = *(const f32x4*)(nb + 0);
      p1 = *(const f32x4*)(nb + 4);
      p2 = *(const f32x4*)(nb + 8);
      p3 = *(const f32x4*)(nb + 12);
    }
    uint4 pk0, pk1;
    pk0.x = (unsigned)f2bf(c0[0]) | ((unsigned)f2bf(c0[1]) << 16);
    pk0.y = (unsigned)f2bf(c0[2]) | ((unsigned)f2bf(c0[3]) << 16);
    pk0.z = (unsigned)f2bf(c1[0]) | ((unsigned)f2bf(c1[1]) << 16);
    pk0.w = (unsigned)f2bf(c1[2]) | ((unsigned)f2bf(c1[3]) << 16);
    pk1.x = (unsigned)f2bf(c2[0]) | ((unsigned)f2bf(c2[1]) << 16);
    pk1.y = (unsigned)f2bf(c2[2]) | ((unsigned)f2bf(c2[3]) << 16);
    pk1.z = (unsigned)f2bf(c3[0]) | ((unsigned)f2bf(c3[1]) << 16);
    pk1.w = (unsigned)f2bf(c3[2]) | ((unsigned)f2bf(c3[3]) << 16);
    *(uint4*)lB = pk0;
    *(uint4*)(lB + 8) = pk1;

    __syncthreads();   // drains vmcnt (gload_lds) + lgkm (ds_write)

    bf16x8 a[4], bfr[4];
#pragma unroll
    for (int i = 0; i < 4; ++i) a[i] = *(const bf16x8*)(baseA + i * 16 * 64);
#pragma unroll
    for (int j = 0; j < 4; ++j) bfr[j] = *(const bf16x8*)(baseB + j * 16 * 64);
#pragma unroll
    for (int i = 0; i < 4; ++i)
#pragma unroll
      for (int j = 0; j < 4; ++j)
        acc[i][j] = __builtin_amdgcn_mfma_f32_16x16x32_bf16(a[i], bfr[j], acc[i][j], 0, 0, 0);
    __syncthreads();
  }

  // epilogue: C[m=hv][n=k]; D row=(lane>>4)*4+e (A-row), col=lane&15 (B-row)
  const int hvb = m0 + wr * 64 + (lane >> 4) * 4;
  const int kc0 = n0 + wc * 64 + (lane & 15);
#pragma unroll
  for (int i = 0; i < 4; ++i) {
#pragma unroll
    for (int j = 0; j < 4; ++j) {
      int kc = kc0 + j * 16;
#pragma unroll
      for (int e = 0; e < 4; ++e) {
        int hv = hvb + i * 16 + e;
        int h = hv >> 5, v = hv & 31;
        vT[((size_t)h * NN + b * VD + v) * NKK + kc] = f2bf(acc[i][j][e]);
      }
    }
  }
}

// ---------------- kernel 2: per (h,q) row: median threshold + masked softmax -> att bf16
__global__ __launch_bounds__(256) void att_kernel(
    const float* __restrict__ m_dist, const float* __restrict__ r,
    unsigned short* __restrict__ att) {
  const int row = blockIdx.x;          // h*NQ + q
  const int h = row >> 11;
  const int t = threadIdx.x;
  const int wid = t >> 6;
  const float* md = m_dist + (size_t)row * NKK;

  __shared__ unsigned int hist[256];
  __shared__ float coll[160];
  __shared__ unsigned int collCnt;
  __shared__ int sBA, sBB;
  __shared__ unsigned int sBelow;
  __shared__ unsigned int wtot[4];
  __shared__ float wmin[4], wsumsh[4];
  __shared__ float sVa, sVb;

  float rr = r[h];
  const float C = (float)(0.25 * 3.141592653589793 * (1.0 - 1e-7));
  float sc = tanf(C * (1.0f + sinf(rr)));

  hist[t] = 0u;
  if (t == 0) collCnt = 0u;
  __syncthreads();

  float m[8];
#pragma unroll
  for (int j = 0; j < 8; ++j) m[j] = md[t + 256 * j];

  float mn = m[0];
#pragma unroll
  for (int j = 1; j < 8; ++j) mn = fminf(mn, m[j]);
#pragma unroll
  for (int j = 0; j < 8; ++j) {
    int bin = (int)(m[j] * 256.0f);
    bin = min(max(bin, 0), 255);
    atomicAdd(&hist[bin], 1u);
  }
#pragma unroll
  for (int off = 32; off > 0; off >>= 1) mn = fminf(mn, __shfl_down(mn, off));
  if ((t & 63) == 0) wmin[wid] = mn;
  __syncthreads();

  // inclusive prefix over 256 bins (bin t owned by thread t)
  unsigned int c = hist[t];
  unsigned int xs2 = c;
  for (int off = 1; off < 64; off <<= 1) {
    unsigned int y = __shfl_up(xs2, off);
    if ((t & 63) >= off) xs2 += y;
  }
  if ((t & 63) == 63) wtot[wid] = xs2;
  __syncthreads();
  unsigned int base = 0;
  for (int wq = 0; wq < 4; ++wq)
    if (wq < wid) base += wtot[wq];
  unsigned int cum = xs2 + base;
  if (cum >= 1024u && cum - c < 1024u) { sBA = t; sBelow = cum - c; }
  if (cum >= 1025u && cum - c < 1025u) { sBB = t; }
  __syncthreads();

  const int bA = sBA, bB = sBB;
  const unsigned int below = sBelow;
#pragma unroll
  for (int j = 0; j < 8; ++j) {
    int bin = (int)(m[j] * 256.0f);
    bin = min(max(bin, 0), 255);
    if (bin >= bA && bin <= bB) {
      unsigned int idx = atomicAdd(&collCnt, 1u);
      if (idx < 160u) coll[idx] = m[j];
    }
  }
  __syncthreads();
  const int n = (int)min(collCnt, 160u);
  const int ra = 1023 - (int)below, rb = 1024 - (int)below;
  if (t < n) {
    float v = coll[t];
    int rank = 0;
    for (int j2 = 0; j2 < n; ++j2) {
      float u = coll[j2];
      rank += (u < v || (u == v && j2 < t)) ? 1 : 0;  // stable rank
    }
    if (rank == ra) sVa = v;
    if (rank == rb) sVb = v;
  }
  __syncthreads();

  float mtot = fminf(fminf(wmin[0], wmin[1]), fminf(wmin[2], wmin[3]));
  float minscaled = mtot * sc;
  float ap = sVa * sc, bp = sVb * sc;
  float thr = 0.5f * ap + 0.5f * bp;   // replicate linear interpolation

  float wv[8];
  float wsum = 0.f;
#pragma unroll
  for (int j = 0; j < 8; ++j) {
    float s = m[j] * sc;
    float e = (s <= thr) ? __expf(minscaled - s) : 0.f;
    wv[j] = e;
    wsum += e;
  }
#pragma unroll
  for (int off = 32; off > 0; off >>= 1) wsum += __shfl_down(wsum, off);
  if ((t & 63) == 0) wsumsh[wid] = wsum;
  __syncthreads();
  float denom = wsumsh[0] + wsumsh[1] + wsumsh[2] + wsumsh[3];
  float inv = 1.0f / denom;

  unsigned short* ao = att + (size_t)row * NKK;
#pragma unroll
  for (int j = 0; j < 8; ++j) ao[t + 256 * j] = f2bf(wv[j] * inv);
}

// ---------------- kernel 3: per head GEMM: C[q, n] = att[h] @ vT[h]^T, + gelu, scattered to out
__global__ __launch_bounds__(256) void gemm_kernel(
    const unsigned short* __restrict__ att, const unsigned short* __restrict__ vT,
    float* __restrict__ out) {
  const int bid = blockIdx.x;
  const int h = bid & 7;           // XCD = bid%8 -> one head per XCD (B panel L2-resident)
  const int tile = bid >> 3;       // 0..63
  const int qt = tile >> 2, nt = tile & 3;
  const int q0 = qt * 128, n0 = nt * 128;
  const int t = threadIdx.x;
  const int lane = t & 63, wid = t >> 6;
  const int wr = wid >> 1, wc = wid & 1;

  __shared__ __align__(16) unsigned short As[128 * 32];
  __shared__ __align__(16) unsigned short Bs[128 * 32];

  const int rowL = t >> 2;          // 0..63
  const int cb = (t & 3) * 8;       // k element offset (16B)

  const unsigned short* gA0 = att + ((size_t)h * NQ + q0 + rowL) * NKK + cb;
  const unsigned short* gA1 = gA0 + (size_t)64 * NKK;
  const unsigned short* gB0 = vT + ((size_t)h * NN + n0 + rowL) * NKK + cb;
  const unsigned short* gB1 = gB0 + (size_t)64 * NKK;

  char* lA0 = (char*)As + t * 16;
  char* lA1 = (char*)As + 4096 + t * 16;
  char* lB0 = (char*)Bs + t * 16;
  char* lB1 = (char*)Bs + 4096 + t * 16;

  f32x4 acc[4][4];
#pragma unroll
  for (int i = 0; i < 4; ++i)
#pragma unroll
    for (int j = 0; j < 4; ++j) acc[i][j] = (f32x4){0.f, 0.f, 0.f, 0.f};

  const int fr = lane & 15;
  const int kb = (lane >> 4) * 16;  // byte offset of 8-elem k group
  const char* baseA = (const char*)As + (wr * 64 + fr) * 64 + kb;
  const char* baseB = (const char*)Bs + (wc * 64 + fr) * 64 + kb;

  for (int kt = 0; kt < NKK / 32; ++kt) {
    gload_lds16(gA0, lA0);
    gload_lds16(gA1, lA1);
    gload_lds16(gB0, lB0);
    gload_lds16(gB1, lB1);
    gA0 += 32; gA1 += 32; gB0 += 32; gB1 += 32;
    __syncthreads();   // drains vmcnt before barrier

    bf16x8 a[4], b[4];
#pragma unroll
    for (int i = 0; i < 4; ++i) a[i] = *(const bf16x8*)(baseA + i * 16 * 64);
#pragma unroll
    for (int j = 0; j < 4; ++j) b[j] = *(const bf16x8*)(baseB + j * 16 * 64);
#pragma unroll
    for (int i = 0; i < 4; ++i)
#pragma unroll
      for (int j = 0; j < 4; ++j)
        acc[i][j] = __builtin_amdgcn_mfma_f32_16x16x32_bf16(a[i], b[j], acc[i][j], 0, 0, 0);
    __syncthreads();
  }

  // epilogue: D row=(lane>>4)*4+reg, col=lane&15 ; n -> (b, v) ; out[b, q, h*32+v]
  const int orow = q0 + wr * 64 + (lane >> 4) * 4;
  const int ocol0 = n0 + wc * 64 + (lane & 15);
#pragma unroll
  for (int i = 0; i < 4; ++i) {
#pragma unroll
    for (int j = 0; j < 4; ++j) {
      int ncol = ocol0 + j * 16;
      int bb = ncol >> 5, vv = ncol & 31;
      float* op = out + ((size_t)bb * NQ + orow + i * 16) * HID + h * VD + vv;
#pragma unroll
      for (int e = 0; e < 4; ++e) op[(size_t)e * HID] = gelu_f(acc[i][j][e]);
    }
  }
}

extern "C" void kernel_launch(void* const* d_in, const int* in_sizes, int n_in,
                              void* d_out, int out_size, void* d_ws, size_t ws_size,
                              hipStream_t stream) {
  const float* m_dist = (const float*)d_in[0];  // [8,2048,2048]
  const float* x      = (const float*)d_in[1];  // [16,2048,256]
  const float* r      = (const float*)d_in[2];  // [8]
  const float* weight = (const float*)d_in[3];  // [8,256,32]
  float* out = (float*)d_out;                   // [16,2048,256]

  // workspace: att bf16 (67.1 MB) + vT bf16 (16.8 MB) + wT bf16 (128 KB)
  unsigned short* att = (unsigned short*)d_ws;
  unsigned short* vT  = (unsigned short*)((char*)d_ws + (size_t)NH * NQ * NKK * 2);
  unsigned short* wT  = (unsigned short*)((char*)d_ws + (size_t)NH * NQ * NKK * 2 +
                                          (size_t)NH * NN * NKK * 2);

  wt_kernel<<<dim3(256), dim3(256), 0, stream>>>(weight, wT);
  value_kernel<<<dim3(32, NB), dim3(256), 0, stream>>>(wT, x, vT);
  att_kernel<<<dim3(NH * NQ), dim3(256), 0, stream>>>(m_dist, r, att);
  gemm_kernel<<<dim3(NH * 64), dim3(256), 0, stream>>>(att, vT, out);
}

// Round 3
// 113.005 us; speedup vs baseline: 1.7462x; 1.0164x over previous
//
#include <hip/hip_runtime.h>
#include <hip/hip_bf16.h>

#define NH   8
#define HID  256
#define VD   32
#define NQ   2048
#define NKK  2048
#define NB   16
#define NN   512   // NB*VD

typedef short bf16x8 __attribute__((ext_vector_type(8)));
typedef float f32x4 __attribute__((ext_vector_type(4)));

__device__ inline unsigned short f2bf(float f) {
  unsigned int u = __float_as_uint(f);
  u += 0x7FFFu + ((u >> 16) & 1u);   // RNE
  return (unsigned short)(u >> 16);
}

__device__ inline void gload_lds16(const void* g, void* l) {
  __builtin_amdgcn_global_load_lds(
      (const __attribute__((address_space(1))) void*)g,
      (__attribute__((address_space(3))) void*)l, 16, 0, 0);
}

__device__ inline float gelu_f(float x) {
  // jax.nn.gelu approximate: 0.5x(1+tanh(u)), tanh via exp (2u in [-20,20], no overflow)
  float u2 = 1.5957691216057308f * (x + 0.044715f * x * x * x);  // 2u
  float e = __expf(u2);
  return 0.5f * x * (1.0f + (e - 1.0f) / (e + 1.0f));
}

// ---------------- kernel 0: wT[h*32+v][j] = bf16(w[h][j][v])
__global__ __launch_bounds__(256) void wt_kernel(
    const float* __restrict__ w, unsigned short* __restrict__ wT) {
  const int n = blockIdx.x;        // 0..255 (h*32+v)
  const int j = threadIdx.x;       // 0..255
  wT[(size_t)n * HID + j] = f2bf(w[(size_t)(n >> 5) * HID * VD + (size_t)j * VD + (n & 31)]);
}

// ---------------- kernel 1: per-b MFMA GEMM: vT[(h,v)][k] = sum_j wT[(h,v)][j] * x[b][k][j]
__global__ __launch_bounds__(256) void value_kernel(
    const unsigned short* __restrict__ wT, const float* __restrict__ x,
    unsigned short* __restrict__ vT) {
  const int hvt = blockIdx.x & 1;      // 0..1  (hv tile)
  const int kt  = blockIdx.x >> 1;     // 0..15 (k tile)
  const int b   = blockIdx.y;          // 0..15
  const int m0 = hvt * 128;            // hv base
  const int n0 = kt * 128;             // k base
  const int t = threadIdx.x;
  const int lane = t & 63, wid = t >> 6;
  const int wr = wid >> 1, wc = wid & 1;

  __shared__ __align__(16) unsigned short As[128 * 32];
  __shared__ __align__(16) unsigned short Bs[128 * 32];

  // A staging via global_load_lds (wT is bf16, K-contig)
  const int rowL = t >> 2, cb = (t & 3) * 8;
  const unsigned short* gA0 = wT + (size_t)(m0 + rowL) * HID + cb;
  const unsigned short* gA1 = gA0 + (size_t)64 * HID;
  char* lA0 = (char*)As + t * 16;
  char* lA1 = (char*)As + 4096 + t * 16;

  // B staging via registers with f32->bf16 (x rows are k-cols of output)
  const int brow = t >> 1, bj = (t & 1) * 16;
  const float* gB = x + ((size_t)b * NKK + n0 + brow) * HID + bj;
  unsigned short* lB = Bs + brow * 32 + bj;

  f32x4 acc[4][4];
#pragma unroll
  for (int i = 0; i < 4; ++i)
#pragma unroll
    for (int j = 0; j < 4; ++j) acc[i][j] = (f32x4){0.f, 0.f, 0.f, 0.f};

  const int fr = lane & 15;
  const int kb = (lane >> 4) * 16;
  const char* baseA = (const char*)As + (wr * 64 + fr) * 64 + kb;
  const char* baseB = (const char*)Bs + (wc * 64 + fr) * 64 + kb;

  // prefetch B step 0
  f32x4 p0 = *(const f32x4*)(gB + 0);
  f32x4 p1 = *(const f32x4*)(gB + 4);
  f32x4 p2 = *(const f32x4*)(gB + 8);
  f32x4 p3 = *(const f32x4*)(gB + 12);

  for (int kk = 0; kk < HID / 32; ++kk) {
    gload_lds16(gA0, lA0);
    gload_lds16(gA1, lA1);
    gA0 += 32; gA1 += 32;

    f32x4 c0 = p0, c1 = p1, c2 = p2, c3 = p3;
    if (kk < HID / 32 - 1) {
      const float* nb = gB + (kk + 1) * 32;
      p0 = *(const f32x4*)(nb + 0);
      p1 = *(const f32x4*)(nb + 4);
      p2 = *(const f32x4*)(nb + 8);
      p3 = *(const f32x4*)(nb + 12);
    }
    uint4 pk0, pk1;
    pk0.x = (unsigned)f2bf(c0[0]) | ((unsigned)f2bf(c0[1]) << 16);
    pk0.y = (unsigned)f2bf(c0[2]) | ((unsigned)f2bf(c0[3]) << 16);
    pk0.z = (unsigned)f2bf(c1[0]) | ((unsigned)f2bf(c1[1]) << 16);
    pk0.w = (unsigned)f2bf(c1[2]) | ((unsigned)f2bf(c1[3]) << 16);
    pk1.x = (unsigned)f2bf(c2[0]) | ((unsigned)f2bf(c2[1]) << 16);
    pk1.y = (unsigned)f2bf(c2[2]) | ((unsigned)f2bf(c2[3]) << 16);
    pk1.z = (unsigned)f2bf(c3[0]) | ((unsigned)f2bf(c3[1]) << 16);
    pk1.w = (unsigned)f2bf(c3[2]) | ((unsigned)f2bf(c3[3]) << 16);
    *(uint4*)lB = pk0;
    *(uint4*)(lB + 8) = pk1;

    __syncthreads();   // drains vmcnt (gload_lds) + lgkm (ds_write)

    bf16x8 a[4], bfr[4];
#pragma unroll
    for (int i = 0; i < 4; ++i) a[i] = *(const bf16x8*)(baseA + i * 16 * 64);
#pragma unroll
    for (int j = 0; j < 4; ++j) bfr[j] = *(const bf16x8*)(baseB + j * 16 * 64);
#pragma unroll
    for (int i = 0; i < 4; ++i)
#pragma unroll
      for (int j = 0; j < 4; ++j)
        acc[i][j] = __builtin_amdgcn_mfma_f32_16x16x32_bf16(a[i], bfr[j], acc[i][j], 0, 0, 0);
    __syncthreads();
  }

  // epilogue: C[m=hv][n=k]; D row=(lane>>4)*4+e (A-row), col=lane&15 (B-row)
  const int hvb = m0 + wr * 64 + (lane >> 4) * 4;
  const int kc0 = n0 + wc * 64 + (lane & 15);
#pragma unroll
  for (int i = 0; i < 4; ++i) {
#pragma unroll
    for (int j = 0; j < 4; ++j) {
      int kc = kc0 + j * 16;
#pragma unroll
      for (int e = 0; e < 4; ++e) {
        int hv = hvb + i * 16 + e;
        int h = hv >> 5, v = hv & 31;
        vT[((size_t)h * NN + b * VD + v) * NKK + kc] = f2bf(acc[i][j][e]);
      }
    }
  }
}

// ---------------- kernel 2: per (h,q) row: median threshold + masked softmax -> att bf16
__global__ __launch_bounds__(256) void att_kernel(
    const float* __restrict__ m_dist, const float* __restrict__ r,
    unsigned short* __restrict__ att) {
  const int row = blockIdx.x;          // h*NQ + q
  const int h = row >> 11;
  const int t = threadIdx.x;
  const int wid = t >> 6;
  const float* md = m_dist + (size_t)row * NKK;

  __shared__ unsigned int hist[256];
  __shared__ float coll[160];
  __shared__ unsigned int collCnt;
  __shared__ int sBA, sBB;
  __shared__ unsigned int sBelow;
  __shared__ unsigned int wtot[4];
  __shared__ float wmin[4], wsumsh[4];
  __shared__ float sVa, sVb;

  float rr = r[h];
  const float C = (float)(0.25 * 3.141592653589793 * (1.0 - 1e-7));
  float sc = tanf(C * (1.0f + sinf(rr)));

  hist[t] = 0u;
  if (t == 0) collCnt = 0u;
  __syncthreads();

  float m[8];
#pragma unroll
  for (int j = 0; j < 8; ++j) m[j] = md[t + 256 * j];

  float mn = m[0];
#pragma unroll
  for (int j = 1; j < 8; ++j) mn = fminf(mn, m[j]);
#pragma unroll
  for (int j = 0; j < 8; ++j) {
    int bin = (int)(m[j] * 256.0f);
    bin = min(max(bin, 0), 255);
    atomicAdd(&hist[bin], 1u);
  }
#pragma unroll
  for (int off = 32; off > 0; off >>= 1) mn = fminf(mn, __shfl_down(mn, off));
  if ((t & 63) == 0) wmin[wid] = mn;
  __syncthreads();

  // inclusive prefix over 256 bins (bin t owned by thread t)
  unsigned int c = hist[t];
  unsigned int xs2 = c;
  for (int off = 1; off < 64; off <<= 1) {
    unsigned int y = __shfl_up(xs2, off);
    if ((t & 63) >= off) xs2 += y;
  }
  if ((t & 63) == 63) wtot[wid] = xs2;
  __syncthreads();
  unsigned int base = 0;
  for (int wq = 0; wq < 4; ++wq)
    if (wq < wid) base += wtot[wq];
  unsigned int cum = xs2 + base;
  if (cum >= 1024u && cum - c < 1024u) { sBA = t; sBelow = cum - c; }
  if (cum >= 1025u && cum - c < 1025u) { sBB = t; }
  __syncthreads();

  const int bA = sBA, bB = sBB;
  const unsigned int below = sBelow;
#pragma unroll
  for (int j = 0; j < 8; ++j) {
    int bin = (int)(m[j] * 256.0f);
    bin = min(max(bin, 0), 255);
    if (bin >= bA && bin <= bB) {
      unsigned int idx = atomicAdd(&collCnt, 1u);
      if (idx < 160u) coll[idx] = m[j];
    }
  }
  __syncthreads();
  const int n = (int)min(collCnt, 160u);
  const int ra = 1023 - (int)below, rb = 1024 - (int)below;
  if (t < n) {
    float v = coll[t];
    int rank = 0;
    for (int j2 = 0; j2 < n; ++j2) {
      float u = coll[j2];
      rank += (u < v || (u == v && j2 < t)) ? 1 : 0;  // stable rank
    }
    if (rank == ra) sVa = v;
    if (rank == rb) sVb = v;
  }
  __syncthreads();

  float mtot = fminf(fminf(wmin[0], wmin[1]), fminf(wmin[2], wmin[3]));
  float minscaled = mtot * sc;
  float ap = sVa * sc, bp = sVb * sc;
  float thr = 0.5f * ap + 0.5f * bp;   // replicate linear interpolation

  float wv[8];
  float wsum = 0.f;
#pragma unroll
  for (int j = 0; j < 8; ++j) {
    float s = m[j] * sc;
    float e = (s <= thr) ? __expf(minscaled - s) : 0.f;
    wv[j] = e;
    wsum += e;
  }
#pragma unroll
  for (int off = 32; off > 0; off >>= 1) wsum += __shfl_down(wsum, off);
  if ((t & 63) == 0) wsumsh[wid] = wsum;
  __syncthreads();
  float denom = wsumsh[0] + wsumsh[1] + wsumsh[2] + wsumsh[3];
  float inv = 1.0f / denom;

  unsigned short* ao = att + (size_t)row * NKK;
#pragma unroll
  for (int j = 0; j < 8; ++j) ao[t + 256 * j] = f2bf(wv[j] * inv);
}

// ---------------- kernel 3: per head GEMM: C[q, n] = att[h] @ vT[h]^T, + gelu, scattered out
// depth-3 pipelined: 4 LDS buffer pairs, counted vmcnt(8), one barrier per K-step
__global__ __launch_bounds__(256) void gemm_kernel(
    const unsigned short* __restrict__ att, const unsigned short* __restrict__ vT,
    float* __restrict__ out) {
  const int bid = blockIdx.x;
  const int h = bid & 7;           // XCD = bid%8 -> one head per XCD (B panel L2-resident)
  const int tile = bid >> 3;       // 0..63
  const int qt = tile >> 2, nt = tile & 3;
  const int q0 = qt * 128, n0 = nt * 128;
  const int t = threadIdx.x;
  const int lane = t & 63, wid = t >> 6;
  const int wr = wid >> 1, wc = wid & 1;

  __shared__ __align__(16) unsigned short As[4][128 * 32];
  __shared__ __align__(16) unsigned short Bs[4][128 * 32];

  const int rowL = t >> 2;          // 0..63
  const int cb = (t & 3) * 8;       // k element offset (16B)

  const unsigned short* gA = att + ((size_t)h * NQ + q0 + rowL) * NKK + cb;
  const unsigned short* gB = vT + ((size_t)h * NN + n0 + rowL) * NKK + cb;
  const int ldsOff = t * 16;

#define STAGE(BI, KT) do {                                                  \
    const unsigned short* a_ = gA + (KT) * 32;                              \
    const unsigned short* b_ = gB + (KT) * 32;                              \
    char* lA_ = (char*)As[(BI)] + ldsOff;                                   \
    char* lB_ = (char*)Bs[(BI)] + ldsOff;                                   \
    gload_lds16(a_, lA_);                                                   \
    gload_lds16(a_ + (size_t)64 * NKK, lA_ + 4096);                         \
    gload_lds16(b_, lB_);                                                   \
    gload_lds16(b_ + (size_t)64 * NKK, lB_ + 4096);                         \
  } while (0)

  f32x4 acc[4][4];
#pragma unroll
  for (int i = 0; i < 4; ++i)
#pragma unroll
    for (int j = 0; j < 4; ++j) acc[i][j] = (f32x4){0.f, 0.f, 0.f, 0.f};

  const int fr = lane & 15;
  const int kb = (lane >> 4) * 16;  // byte offset of 8-elem k group
  const int fragOff = (wr * 64 + fr) * 64 + kb;   // A-side byte offset
  const int fragOffB = (wc * 64 + fr) * 64 + kb;  // B-side byte offset

  // prologue: 3 tiles in flight
  STAGE(0, 0);
  STAGE(1, 1);
  STAGE(2, 2);
  asm volatile("s_waitcnt vmcnt(8)\n\ts_barrier" ::: "memory");  // tile 0 ready

  for (int kt = 0; kt < 64; kt += 4) {
#pragma unroll
    for (int u = 0; u < 4; ++u) {
      // frag reads from buffer u (tile kt+u)
      const char* bA = (const char*)As[u] + fragOff;
      const char* bB = (const char*)Bs[u] + fragOffB;
      bf16x8 a[4], b[4];
#pragma unroll
      for (int i = 0; i < 4; ++i) a[i] = *(const bf16x8*)(bA + i * 1024);
#pragma unroll
      for (int j = 0; j < 4; ++j) b[j] = *(const bf16x8*)(bB + j * 1024);
      // stage tile kt+u+3 into buffer (u+3)&3 (consumed last sub-iter); wrap at tail
      STAGE((u + 3) & 3, (kt + u + 3) & 63);
#pragma unroll
      for (int i = 0; i < 4; ++i)
#pragma unroll
        for (int j = 0; j < 4; ++j)
          acc[i][j] = __builtin_amdgcn_mfma_f32_16x16x32_bf16(a[i], b[j], acc[i][j], 0, 0, 0);
      // keep 8 loads (2 tiles) in flight; oldest tile (next to read) retired
      asm volatile("s_waitcnt vmcnt(8)\n\ts_barrier" ::: "memory");
    }
  }
  // drain junk tail stages before LDS deallocates / epilogue
  asm volatile("s_waitcnt vmcnt(0)" ::: "memory");
#undef STAGE

  // epilogue: D row=(lane>>4)*4+reg, col=lane&15 ; n -> (b, v) ; out[b, q, h*32+v]
  const int orow = q0 + wr * 64 + (lane >> 4) * 4;
  const int ocol0 = n0 + wc * 64 + (lane & 15);
#pragma unroll
  for (int i = 0; i < 4; ++i) {
#pragma unroll
    for (int j = 0; j < 4; ++j) {
      int ncol = ocol0 + j * 16;
      int bb = ncol >> 5, vv = ncol & 31;
      float* op = out + ((size_t)bb * NQ + orow + i * 16) * HID + h * VD + vv;
#pragma unroll
      for (int e = 0; e < 4; ++e) op[(size_t)e * HID] = gelu_f(acc[i][j][e]);
    }
  }
}

extern "C" void kernel_launch(void* const* d_in, const int* in_sizes, int n_in,
                              void* d_out, int out_size, void* d_ws, size_t ws_size,
                              hipStream_t stream) {
  const float* m_dist = (const float*)d_in[0];  // [8,2048,2048]
  const float* x      = (const float*)d_in[1];  // [16,2048,256]
  const float* r      = (const float*)d_in[2];  // [8]
  const float* weight = (const float*)d_in[3];  // [8,256,32]
  float* out = (float*)d_out;                   // [16,2048,256]

  // workspace: att bf16 (67.1 MB) + vT bf16 (16.8 MB) + wT bf16 (128 KB)
  unsigned short* att = (unsigned short*)d_ws;
  unsigned short* vT  = (unsigned short*)((char*)d_ws + (size_t)NH * NQ * NKK * 2);
  unsigned short* wT  = (unsigned short*)((char*)d_ws + (size_t)NH * NQ * NKK * 2 +
                                          (size_t)NH * NN * NKK * 2);

  wt_kernel<<<dim3(256), dim3(256), 0, stream>>>(weight, wT);
  value_kernel<<<dim3(32, NB), dim3(256), 0, stream>>>(wT, x, vT);
  att_kernel<<<dim3(NH * NQ), dim3(256), 0, stream>>>(m_dist, r, att);
  gemm_kernel<<<dim3(NH * 64), dim3(256), 0, stream>>>(att, vT, out);
}

// Round 4
// 112.576 us; speedup vs baseline: 1.7529x; 1.0038x over previous
//
#include <hip/hip_runtime.h>
#include <hip/hip_bf16.h>

#define NH   8
#define HID  256
#define VD   32
#define NQ   2048
#define NKK  2048
#define NB   16
#define NN   512   // NB*VD

typedef short bf16x8 __attribute__((ext_vector_type(8)));
typedef float f32x4 __attribute__((ext_vector_type(4)));

__device__ inline unsigned short f2bf(float f) {
  unsigned int u = __float_as_uint(f);
  u += 0x7FFFu + ((u >> 16) & 1u);   // RNE
  return (unsigned short)(u >> 16);
}

__device__ inline void gload_lds16(const void* g, void* l) {
  __builtin_amdgcn_global_load_lds(
      (const __attribute__((address_space(1))) void*)g,
      (__attribute__((address_space(3))) void*)l, 16, 0, 0);
}

__device__ inline float gelu_f(float x) {
  // jax.nn.gelu approximate: 0.5x(1+tanh(u)), tanh via exp (2u in [-20,20], no overflow)
  float u2 = 1.5957691216057308f * (x + 0.044715f * x * x * x);  // 2u
  float e = __expf(u2);
  return 0.5f * x * (1.0f + (e - 1.0f) / (e + 1.0f));
}

// LDS tile swizzle (T2): 16B slot s of row r holds logical slot s ^ ((r>>1)&3).
// Read pattern becomes 2-way bank aliasing (free); staging source pre-swizzled.

// ---------------- kernel 0: wT[h*32+v][j] = bf16(w[h][j][v])
__global__ __launch_bounds__(256) void wt_kernel(
    const float* __restrict__ w, unsigned short* __restrict__ wT) {
  const int n = blockIdx.x;        // 0..255 (h*32+v)
  const int j = threadIdx.x;       // 0..255
  wT[(size_t)n * HID + j] = f2bf(w[(size_t)(n >> 5) * HID * VD + (size_t)j * VD + (n & 31)]);
}

// ---------------- kernel 1: per-b MFMA GEMM: vT[(h,v)][k] = sum_j wT[(h,v)][j] * x[b][k][j]
__global__ __launch_bounds__(256) void value_kernel(
    const unsigned short* __restrict__ wT, const float* __restrict__ x,
    unsigned short* __restrict__ vT) {
  const int hvt = blockIdx.x & 1;      // 0..1  (hv tile)
  const int kt  = blockIdx.x >> 1;     // 0..15 (k tile)
  const int b   = blockIdx.y;          // 0..15
  const int m0 = hvt * 128;            // hv base
  const int n0 = kt * 128;             // k base
  const int t = threadIdx.x;
  const int lane = t & 63, wid = t >> 6;
  const int wr = wid >> 1, wc = wid & 1;

  __shared__ __align__(16) unsigned short As[128 * 32];
  __shared__ __align__(16) unsigned short Bs[128 * 32];

  // A staging via global_load_lds (wT is bf16, K-contig); source k pre-swizzled
  const int rowL = t >> 2;
  const int cb = (((t & 3) ^ ((t >> 3) & 3)) * 8);
  const unsigned short* gA0 = wT + (size_t)(m0 + rowL) * HID + cb;
  const unsigned short* gA1 = gA0 + (size_t)64 * HID;
  char* lA0 = (char*)As + t * 16;
  char* lA1 = (char*)As + 4096 + t * 16;

  // B staging via registers with f32->bf16 (x rows are k-cols of output)
  const int brow = t >> 1, bj = (t & 1) * 16;
  const float* gB = x + ((size_t)b * NKK + n0 + brow) * HID + bj;
  const int bc = (brow >> 1) & 3;
  const int bs0 = (2 * (t & 1)) ^ bc;          // physical 16B slot for first uint4
  unsigned short* lB0 = Bs + brow * 32 + bs0 * 8;
  unsigned short* lB1 = Bs + brow * 32 + (bs0 ^ 1) * 8;

  f32x4 acc[4][4];
#pragma unroll
  for (int i = 0; i < 4; ++i)
#pragma unroll
    for (int j = 0; j < 4; ++j) acc[i][j] = (f32x4){0.f, 0.f, 0.f, 0.f};

  const int fr = lane & 15;
  const int kb = (((lane >> 4) ^ ((fr >> 1) & 3)) * 16);   // swizzled read slot
  const char* baseA = (const char*)As + (wr * 64 + fr) * 64 + kb;
  const char* baseB = (const char*)Bs + (wc * 64 + fr) * 64 + kb;

  // prefetch B step 0
  f32x4 p0 = *(const f32x4*)(gB + 0);
  f32x4 p1 = *(const f32x4*)(gB + 4);
  f32x4 p2 = *(const f32x4*)(gB + 8);
  f32x4 p3 = *(const f32x4*)(gB + 12);

  for (int kk = 0; kk < HID / 32; ++kk) {
    gload_lds16(gA0, lA0);
    gload_lds16(gA1, lA1);
    gA0 += 32; gA1 += 32;

    f32x4 c0 = p0, c1 = p1, c2 = p2, c3 = p3;
    if (kk < HID / 32 - 1) {
      const float* nb = gB + (kk + 1) * 32;
      p0 = *(const f32x4*)(nb + 0);
      p1 = *(const f32x4*)(nb + 4);
      p2 = *(const f32x4*)(nb + 8);
      p3 = *(const f32x4*)(nb + 12);
    }
    uint4 pk0, pk1;
    pk0.x = (unsigned)f2bf(c0[0]) | ((unsigned)f2bf(c0[1]) << 16);
    pk0.y = (unsigned)f2bf(c0[2]) | ((unsigned)f2bf(c0[3]) << 16);
    pk0.z = (unsigned)f2bf(c1[0]) | ((unsigned)f2bf(c1[1]) << 16);
    pk0.w = (unsigned)f2bf(c1[2]) | ((unsigned)f2bf(c1[3]) << 16);
    pk1.x = (unsigned)f2bf(c2[0]) | ((unsigned)f2bf(c2[1]) << 16);
    pk1.y = (unsigned)f2bf(c2[2]) | ((unsigned)f2bf(c2[3]) << 16);
    pk1.z = (unsigned)f2bf(c3[0]) | ((unsigned)f2bf(c3[1]) << 16);
    pk1.w = (unsigned)f2bf(c3[2]) | ((unsigned)f2bf(c3[3]) << 16);
    *(uint4*)lB0 = pk0;
    *(uint4*)lB1 = pk1;

    __syncthreads();   // drains vmcnt (gload_lds) + lgkm (ds_write)

    bf16x8 a[4], bfr[4];
#pragma unroll
    for (int i = 0; i < 4; ++i) a[i] = *(const bf16x8*)(baseA + i * 16 * 64);
#pragma unroll
    for (int j = 0; j < 4; ++j) bfr[j] = *(const bf16x8*)(baseB + j * 16 * 64);
#pragma unroll
    for (int i = 0; i < 4; ++i)
#pragma unroll
      for (int j = 0; j < 4; ++j)
        acc[i][j] = __builtin_amdgcn_mfma_f32_16x16x32_bf16(a[i], bfr[j], acc[i][j], 0, 0, 0);
    __syncthreads();
  }

  // epilogue: C[m=hv][n=k]; D row=(lane>>4)*4+e (A-row), col=lane&15 (B-row)
  const int hvb = m0 + wr * 64 + (lane >> 4) * 4;
  const int kc0 = n0 + wc * 64 + (lane & 15);
#pragma unroll
  for (int i = 0; i < 4; ++i) {
#pragma unroll
    for (int j = 0; j < 4; ++j) {
      int kc = kc0 + j * 16;
#pragma unroll
      for (int e = 0; e < 4; ++e) {
        int hv = hvb + i * 16 + e;
        int h = hv >> 5, v = hv & 31;
        vT[((size_t)h * NN + b * VD + v) * NKK + kc] = f2bf(acc[i][j][e]);
      }
    }
  }
}

// ---------------- kernel 2: per (h,q) row: median threshold + masked softmax -> att bf16
__global__ __launch_bounds__(256) void att_kernel(
    const float* __restrict__ m_dist, const float* __restrict__ r,
    unsigned short* __restrict__ att) {
  const int row = blockIdx.x;          // h*NQ + q
  const int h = row >> 11;
  const int t = threadIdx.x;
  const int wid = t >> 6;
  const float* md = m_dist + (size_t)row * NKK;

  __shared__ unsigned int hist[256];
  __shared__ float coll[160];
  __shared__ unsigned int collCnt;
  __shared__ int sBA, sBB;
  __shared__ unsigned int sBelow;
  __shared__ unsigned int wtot[4];
  __shared__ float wmin[4], wsumsh[4];
  __shared__ float sVa, sVb;

  float rr = r[h];
  const float C = (float)(0.25 * 3.141592653589793 * (1.0 - 1e-7));
  float sc = tanf(C * (1.0f + sinf(rr)));

  hist[t] = 0u;
  if (t == 0) collCnt = 0u;
  __syncthreads();

  float m[8];
#pragma unroll
  for (int j = 0; j < 8; ++j) m[j] = md[t + 256 * j];

  float mn = m[0];
#pragma unroll
  for (int j = 1; j < 8; ++j) mn = fminf(mn, m[j]);
#pragma unroll
  for (int j = 0; j < 8; ++j) {
    int bin = (int)(m[j] * 256.0f);
    bin = min(max(bin, 0), 255);
    atomicAdd(&hist[bin], 1u);
  }
#pragma unroll
  for (int off = 32; off > 0; off >>= 1) mn = fminf(mn, __shfl_down(mn, off));
  if ((t & 63) == 0) wmin[wid] = mn;
  __syncthreads();

  // inclusive prefix over 256 bins (bin t owned by thread t)
  unsigned int c = hist[t];
  unsigned int xs2 = c;
  for (int off = 1; off < 64; off <<= 1) {
    unsigned int y = __shfl_up(xs2, off);
    if ((t & 63) >= off) xs2 += y;
  }
  if ((t & 63) == 63) wtot[wid] = xs2;
  __syncthreads();
  unsigned int base = 0;
  for (int wq = 0; wq < 4; ++wq)
    if (wq < wid) base += wtot[wq];
  unsigned int cum = xs2 + base;
  if (cum >= 1024u && cum - c < 1024u) { sBA = t; sBelow = cum - c; }
  if (cum >= 1025u && cum - c < 1025u) { sBB = t; }
  __syncthreads();

  const int bA = sBA, bB = sBB;
  const unsigned int below = sBelow;
#pragma unroll
  for (int j = 0; j < 8; ++j) {
    int bin = (int)(m[j] * 256.0f);
    bin = min(max(bin, 0), 255);
    if (bin >= bA && bin <= bB) {
      unsigned int idx = atomicAdd(&collCnt, 1u);
      if (idx < 160u) coll[idx] = m[j];
    }
  }
  __syncthreads();
  const int n = (int)min(collCnt, 160u);
  const int ra = 1023 - (int)below, rb = 1024 - (int)below;
  if (t < n) {
    float v = coll[t];
    int rank = 0;
    for (int j2 = 0; j2 < n; ++j2) {
      float u = coll[j2];
      rank += (u < v || (u == v && j2 < t)) ? 1 : 0;  // stable rank
    }
    if (rank == ra) sVa = v;
    if (rank == rb) sVb = v;
  }
  __syncthreads();

  float mtot = fminf(fminf(wmin[0], wmin[1]), fminf(wmin[2], wmin[3]));
  float minscaled = mtot * sc;
  float ap = sVa * sc, bp = sVb * sc;
  float thr = 0.5f * ap + 0.5f * bp;   // replicate linear interpolation

  float wv[8];
  float wsum = 0.f;
#pragma unroll
  for (int j = 0; j < 8; ++j) {
    float s = m[j] * sc;
    float e = (s <= thr) ? __expf(minscaled - s) : 0.f;
    wv[j] = e;
    wsum += e;
  }
#pragma unroll
  for (int off = 32; off > 0; off >>= 1) wsum += __shfl_down(wsum, off);
  if ((t & 63) == 0) wsumsh[wid] = wsum;
  __syncthreads();
  float denom = wsumsh[0] + wsumsh[1] + wsumsh[2] + wsumsh[3];
  float inv = 1.0f / denom;

  unsigned short* ao = att + (size_t)row * NKK;
#pragma unroll
  for (int j = 0; j < 8; ++j) ao[t + 256 * j] = f2bf(wv[j] * inv);
}

// ---------------- kernel 3: per head GEMM: C[q, n] = att[h] @ vT[h]^T, + gelu, scattered out
// depth-3 pipelined: 4 LDS buffer pairs, counted vmcnt(8), one barrier per K-step
__global__ __launch_bounds__(256) void gemm_kernel(
    const unsigned short* __restrict__ att, const unsigned short* __restrict__ vT,
    float* __restrict__ out) {
  const int bid = blockIdx.x;
  const int h = bid & 7;           // XCD = bid%8 -> one head per XCD (B panel L2-resident)
  const int tile = bid >> 3;       // 0..63
  const int qt = tile >> 2, nt = tile & 3;
  const int q0 = qt * 128, n0 = nt * 128;
  const int t = threadIdx.x;
  const int lane = t & 63, wid = t >> 6;
  const int wr = wid >> 1, wc = wid & 1;

  __shared__ __align__(16) unsigned short As[4][128 * 32];
  __shared__ __align__(16) unsigned short Bs[4][128 * 32];

  const int rowL = t >> 2;          // 0..63
  const int cb = (((t & 3) ^ ((t >> 3) & 3)) * 8);   // pre-swizzled source k offset

  const unsigned short* gA = att + ((size_t)h * NQ + q0 + rowL) * NKK + cb;
  const unsigned short* gB = vT + ((size_t)h * NN + n0 + rowL) * NKK + cb;
  const int ldsOff = t * 16;

#define STAGE(BI, KT) do {                                                  \
    const unsigned short* a_ = gA + (KT) * 32;                              \
    const unsigned short* b_ = gB + (KT) * 32;                              \
    char* lA_ = (char*)As[(BI)] + ldsOff;                                   \
    char* lB_ = (char*)Bs[(BI)] + ldsOff;                                   \
    gload_lds16(a_, lA_);                                                   \
    gload_lds16(a_ + (size_t)64 * NKK, lA_ + 4096);                         \
    gload_lds16(b_, lB_);                                                   \
    gload_lds16(b_ + (size_t)64 * NKK, lB_ + 4096);                         \
  } while (0)

  f32x4 acc[4][4];
#pragma unroll
  for (int i = 0; i < 4; ++i)
#pragma unroll
    for (int j = 0; j < 4; ++j) acc[i][j] = (f32x4){0.f, 0.f, 0.f, 0.f};

  const int fr = lane & 15;
  const int kb = (((lane >> 4) ^ ((fr >> 1) & 3)) * 16);   // swizzled read slot
  const int fragOff = (wr * 64 + fr) * 64 + kb;   // A-side byte offset
  const int fragOffB = (wc * 64 + fr) * 64 + kb;  // B-side byte offset

  // prologue: 3 tiles in flight
  STAGE(0, 0);
  STAGE(1, 1);
  STAGE(2, 2);
  asm volatile("s_waitcnt vmcnt(8)\n\ts_barrier" ::: "memory");  // tile 0 ready

  for (int kt = 0; kt < 64; kt += 4) {
#pragma unroll
    for (int u = 0; u < 4; ++u) {
      // frag reads from buffer u (tile kt+u)
      const char* bA = (const char*)As[u] + fragOff;
      const char* bB = (const char*)Bs[u] + fragOffB;
      bf16x8 a[4], b[4];
#pragma unroll
      for (int i = 0; i < 4; ++i) a[i] = *(const bf16x8*)(bA + i * 1024);
#pragma unroll
      for (int j = 0; j < 4; ++j) b[j] = *(const bf16x8*)(bB + j * 1024);
      // stage tile kt+u+3 into buffer (u+3)&3 (consumed last sub-iter); wrap at tail
      STAGE((u + 3) & 3, (kt + u + 3) & 63);
#pragma unroll
      for (int i = 0; i < 4; ++i)
#pragma unroll
        for (int j = 0; j < 4; ++j)
          acc[i][j] = __builtin_amdgcn_mfma_f32_16x16x32_bf16(a[i], b[j], acc[i][j], 0, 0, 0);
      // keep 8 loads (2 tiles) in flight; oldest tile (next to read) retired
      asm volatile("s_waitcnt vmcnt(8)\n\ts_barrier" ::: "memory");
    }
  }
  // drain junk tail stages before LDS deallocates / epilogue
  asm volatile("s_waitcnt vmcnt(0)" ::: "memory");
#undef STAGE

  // epilogue: D row=(lane>>4)*4+reg, col=lane&15 ; n -> (b, v) ; out[b, q, h*32+v]
  const int orow = q0 + wr * 64 + (lane >> 4) * 4;
  const int ocol0 = n0 + wc * 64 + (lane & 15);
#pragma unroll
  for (int i = 0; i < 4; ++i) {
#pragma unroll
    for (int j = 0; j < 4; ++j) {
      int ncol = ocol0 + j * 16;
      int bb = ncol >> 5, vv = ncol & 31;
      float* op = out + ((size_t)bb * NQ + orow + i * 16) * HID + h * VD + vv;
#pragma unroll
      for (int e = 0; e < 4; ++e) op[(size_t)e * HID] = gelu_f(acc[i][j][e]);
    }
  }
}

extern "C" void kernel_launch(void* const* d_in, const int* in_sizes, int n_in,
                              void* d_out, int out_size, void* d_ws, size_t ws_size,
                              hipStream_t stream) {
  const float* m_dist = (const float*)d_in[0];  // [8,2048,2048]
  const float* x      = (const float*)d_in[1];  // [16,2048,256]
  const float* r      = (const float*)d_in[2];  // [8]
  const float* weight = (const float*)d_in[3];  // [8,256,32]
  float* out = (float*)d_out;                   // [16,2048,256]

  // workspace: att bf16 (67.1 MB) + vT bf16 (16.8 MB) + wT bf16 (128 KB)
  unsigned short* att = (unsigned short*)d_ws;
  unsigned short* vT  = (unsigned short*)((char*)d_ws + (size_t)NH * NQ * NKK * 2);
  unsigned short* wT  = (unsigned short*)((char*)d_ws + (size_t)NH * NQ * NKK * 2 +
                                          (size_t)NH * NN * NKK * 2);

  wt_kernel<<<dim3(256), dim3(256), 0, stream>>>(weight, wT);
  value_kernel<<<dim3(32, NB), dim3(256), 0, stream>>>(wT, x, vT);
  att_kernel<<<dim3(NH * NQ), dim3(256), 0, stream>>>(m_dist, r, att);
  gemm_kernel<<<dim3(NH * 64), dim3(256), 0, stream>>>(att, vT, out);
}